// Round 6
// baseline (126.782 us; speedup 1.0000x reference)
//
#include <hip/hip_runtime.h>
#include <hip/hip_bf16.h>

#define N_PTS   40000
#define N_B     2
#define N_P     128
#define N_K     32
#define N_KC    4
#define N_FEAT  128
#define NQ2     (N_B * N_P * N_K)   // 8192
#define BIGF    3.0e38f

#define K1SUB   8
#define K1RANGE (N_PTS / K1SUB)     // 5000
#define QCAP1   512                 // knn1 cap (E[n]=341)
#define LBUF1   320                 // knn1 per-block LDS buffer

#define QCAP    96                  // knn2 per-query cap (E[n]=42)

#define TAU2    4.0e-3f             // (2.2*r4)^2 ; tau=0.0632
#define TAU1    1.6e-2f             // (2.2*r32)^2

#define NG      15                  // grid cells per dim; h=1/15 > tau2
#define NCELL   (NG * NG * NG)      // 3375
#define GB_BLK  20                  // grid-build blocks per batch
#define GB_PER  (N_PTS / GB_BLK)    // 2000 pts per block

#define NLOSSB  2048                // loss blocks (4 waves each = 8192 queries)
#define LSCALE  (50.0f / 8192.0f)

// Globals (zero-init at load; consumers reset their own counters each call).
__device__ int    g_sidx[N_P];
__device__ int    g_fidx[NQ2];
__device__ int    g_q1cnt[256];
__device__ unsigned long long g_q1list[256 * QCAP1];   // 1 MB
__device__ int    g_bincnt[N_B * NCELL];               // histogram (reset by scan)
__device__ int    g_binstart[N_B * (NCELL + 1)];
__device__ int    g_cursor[N_B * NCELL];               // scatter cursors
__device__ float4 g_cpts[N_B * N_PTS];                 // bin-sorted clean pts (x,y,z,pp)
__device__ int    g_cpidx[N_B * N_PTS];                // original indices
__device__ float  g_M3[9];
__device__ float  g_WxS[9];

__device__ __forceinline__ int clampi(int v, int lo, int hi) { return v < lo ? lo : (v > hi ? hi : v); }

__device__ __forceinline__ unsigned long long packkey(float d, int idx)
{
    unsigned int u = __float_as_uint(d);
    u ^= (u >> 31) ? 0xFFFFFFFFu : 0x80000000u;
    return ((unsigned long long)u << 32) | (unsigned int)idx;
}

__device__ __forceinline__ int cell_of(float x, float y, float z)
{
    const int cx = clampi((int)(x * NG), 0, NG - 1);
    const int cy = clampi((int)(y * NG), 0, NG - 1);
    const int cz = clampi((int)(z * NG), 0, NG - 1);
    return cx + NG * (cy + NG * cz);
}

// ---------------------------------------------------------------------------
// Launch 1: grid histogram (blocks 0..39) + sidx decode / M3 / WxS / out=0
// (block 40). R1 lesson: no in-kernel cross-block finishers (fence storm).
// ---------------------------------------------------------------------------
__global__ __launch_bounds__(256) void setup_kernel(
    const float* __restrict__ clean,
    const void*  __restrict__ sidx_raw,
    const float* __restrict__ Wf,
    const float* __restrict__ Wx,
    const float* __restrict__ Wc,
    float* __restrict__ out)
{
    __shared__ int hist[NCELL];     // 13.5 KB
    __shared__ int flags[4];
    const int blk = blockIdx.x;
    const int tid = threadIdx.x;

    if (blk < N_B * GB_BLK) {
        // ------- grid histogram (verbatim) -------
        const int bb = blk / GB_BLK;
        const int sb = blk % GB_BLK;
        const float* cb = clean + bb * (N_PTS * 3);

        for (int i = tid; i < NCELL; i += 256) hist[i] = 0;
        __syncthreads();

        const int j0 = sb * GB_PER;
        for (int j = j0 + tid; j < j0 + GB_PER; j += 256) {
            const float x = cb[j * 3 + 0], y = cb[j * 3 + 1], z = cb[j * 3 + 2];
            atomicAdd(&hist[cell_of(x, y, z)], 1);
        }
        __syncthreads();

        for (int i = tid; i < NCELL; i += 256) {
            const int v = hist[i];
            if (v) atomicAdd(&g_bincnt[bb * NCELL + i], v);   // no-return: pipelines freely
        }
    } else {
        // ------- hoisted M3/Wx + sidx dtype-vote decode (verbatim) + out=0 ---
        if (tid == 0) out[0] = 0.0f;       // consumed by launch 4's atomics
        if (tid < 9) {
            const int d = tid / 3, e = tid % 3;
            float acc = 0.0f;
            for (int f0 = 0; f0 < N_FEAT; ++f0)
                acc += Wf[d * N_FEAT + f0] * Wc[f0 * 3 + e];
            g_M3[tid]  = acc;
            g_WxS[tid] = Wx[tid];
        }
        if (tid == 0) { flags[0] = 1; flags[1] = 1; flags[2] = 1; flags[3] = 1; }
        __syncthreads();
        const int*       p32 = (const int*)sidx_raw;
        const long long* p64 = (const long long*)sidx_raw;
        const float*     pf  = (const float*)sidx_raw;
        if (tid < 128) {
            const int       v32 = p32[tid];
            const long long v64 = p64[tid];
            const float     vf  = pf[tid];
            if (!(v32 >= 0 && v32 < N_PTS)) atomicAnd(&flags[0], 0);
            if ((tid & 1) && v32 != 0)      atomicAnd(&flags[1], 0);
            if (!(v64 >= 0 && v64 < N_PTS)) atomicAnd(&flags[2], 0);
            if (!(vf >= 0.0f && vf < (float)N_PTS && vf == floorf(vf))) atomicAnd(&flags[3], 0);
        }
        __syncthreads();
        if (tid < 128) {
            int si;
            if (flags[0] && !(flags[1] && flags[2])) si = p32[tid];
            else if (flags[2])                       si = (int)p64[tid];
            else if (flags[3])                       si = (int)(pf[tid] + 0.5f);
            else                                     si = 0;
            g_sidx[tid] = clampi(si, 0, N_PTS - 1);
        }
    }
}

// ---------------------------------------------------------------------------
// Launch 2: grid prefix scan (blocks 0..1) + knn1 tau-scan (blocks 2..2049).
// ---------------------------------------------------------------------------
__global__ __launch_bounds__(256) void scan_knn1_kernel(
    const float* __restrict__ noisy)
{
    __shared__ unsigned long long buf[LBUF1];  // knn1 branch
    __shared__ int lcnt;
    __shared__ int base_s;
    __shared__ int wsum[4], woff[4];           // scan branch
    const int blk = blockIdx.x;
    const int tid = threadIdx.x;

    if (blk < N_B) {
        // ------- prefix scan + cursor init + bincnt reset (verbatim) -------
        const int bb   = blk;
        const int lane = tid & 63, wv = tid >> 6;

        int lvals[14];
        int lsum = 0;
#pragma unroll
        for (int t = 0; t < 14; ++t) {
            const int idx = tid * 14 + t;
            lvals[t] = (idx < NCELL) ? g_bincnt[bb * NCELL + idx] : 0;
            lsum += lvals[t];
        }
        int v = lsum;
#pragma unroll
        for (int off = 1; off < 64; off <<= 1) {
            const int n = __shfl_up(v, off);
            if (lane >= off) v += n;
        }
        if (lane == 63) wsum[wv] = v;
        __syncthreads();
        if (tid == 0) { int r = 0; for (int w = 0; w < 4; ++w) { woff[w] = r; r += wsum[w]; } }
        __syncthreads();

        int run = woff[wv] + (v - lsum);    // exclusive prefix for this thread's chunk
#pragma unroll
        for (int t = 0; t < 14; ++t) {
            const int idx = tid * 14 + t;
            if (idx < NCELL) {
                g_binstart[bb * (NCELL + 1) + idx] = run;
                g_cursor[bb * NCELL + idx] = run;
                g_bincnt[bb * NCELL + idx] = 0;    // reset for next call
                run += lvals[t];
            }
        }
        if (tid == 0) g_binstart[bb * (NCELL + 1) + NCELL] = N_PTS;
    } else {
        // ------- knn1 LDS-buffered tau-append (verbatim; flattened grid) -------
        const int idx = blk - N_B;
        const int qb  = idx & 255;
        const int sub = idx >> 8;
        const int b   = qb >> 7;
        const int p   = qb & 127;
        const float* nb = noisy + b * (N_PTS * 3);

        if (tid == 0) lcnt = 0;
        const int si = g_sidx[p];
        const float qx = nb[si * 3 + 0];
        const float qy = nb[si * 3 + 1];
        const float qz = nb[si * 3 + 2];
        __syncthreads();

        const int jbeg = sub * K1RANGE;
        const int jend = jbeg + K1RANGE;
        for (int j = jbeg + tid; j < jend; j += 256) {
            const float dx = qx - nb[j * 3 + 0];
            const float dy = qy - nb[j * 3 + 1];
            const float dz = qz - nb[j * 3 + 2];
            const float d2 = fmaf(dz, dz, fmaf(dy, dy, dx * dx));
            if (d2 < TAU1) {
                const int slot = atomicAdd(&lcnt, 1);
                if (slot < LBUF1)
                    buf[slot] = ((unsigned long long)__float_as_uint(d2) << 32) | (unsigned int)j;
            }
        }
        __syncthreads();

        const int cnt = lcnt;
        if (tid == 0) {
            const int add = (cnt <= LBUF1) ? cnt : (QCAP1 + 1000);
            base_s = atomicAdd(&g_q1cnt[qb], add);
        }
        __syncthreads();

        const int base = base_s;
        const int n = (cnt < LBUF1) ? cnt : LBUF1;
        for (int i = tid; i < n; i += 256) {
            const int o = base + i;
            if (o < QCAP1) g_q1list[qb * QCAP1 + o] = buf[i];
        }
    }
}

// ---------------------------------------------------------------------------
// Launch 3: knn1 merge (blocks 0..255) + grid scatter (blocks 256..295).
// ---------------------------------------------------------------------------
__global__ __launch_bounds__(256) void merge_scatter_kernel(
    const float* __restrict__ noisy,
    const float* __restrict__ clean)
{
    __shared__ unsigned long long keys[2048];
    const int blk = blockIdx.x;
    const int tid = threadIdx.x;

    if (blk >= 256) {
        // ------- scatter via low-contention cursor atomics (verbatim) -------
        const int idx = blk - 256;
        const int bb  = idx / GB_BLK;
        const int sb  = idx % GB_BLK;
        const float* cb = clean + bb * (N_PTS * 3);

        const int j0 = sb * GB_PER;
        for (int j = j0 + tid; j < j0 + GB_PER; j += 256) {
            const float x = cb[j * 3 + 0], y = cb[j * 3 + 1], z = cb[j * 3 + 2];
            const int c = cell_of(x, y, z);
            const int pos = atomicAdd(&g_cursor[bb * NCELL + c], 1);
            const float pp = fmaf(z, z, fmaf(y, y, x * x));
            g_cpts[bb * N_PTS + pos]  = make_float4(x, y, z, pp);
            g_cpidx[bb * N_PTS + pos] = j;
        }
        return;
    }

    // ------- knn1 merge: 512-key bitonic; inline exact fallback (verbatim) -------
    const int qb  = blk;
    const int cnt = g_q1cnt[qb];

    if (cnt >= 32 && cnt <= QCAP1) {
        for (int i = tid; i < QCAP1; i += 256)
            keys[i] = (i < cnt) ? g_q1list[qb * QCAP1 + i] : ~0ULL;
        __syncthreads();
        for (int k = 2; k <= QCAP1; k <<= 1) {
            for (int jj = k >> 1; jj > 0; jj >>= 1) {
                const int idx = tid;
                const int i = ((idx & ~(jj - 1)) << 1) | (idx & (jj - 1));
                const int partner = i | jj;
                const bool asc = ((i & k) == 0);
                const unsigned long long a = keys[i];
                const unsigned long long c = keys[partner];
                if ((a > c) == asc) { keys[i] = c; keys[partner] = a; }
                __syncthreads();
            }
        }
    } else {
        const int b = qb >> 7;
        const float* nb = noisy + b * (N_PTS * 3);
        const int si = g_sidx[qb & 127];
        const float qx = nb[si * 3 + 0];
        const float qy = nb[si * 3 + 1];
        const float qz = nb[si * 3 + 2];

        float bd[8]; int bi[8];
#pragma unroll
        for (int i = 0; i < 8; ++i) { bd[i] = BIGF; bi[i] = 0x7fffffff; }
        for (int j = tid; j < N_PTS; j += 256) {
            const float dx = qx - nb[j * 3 + 0];
            const float dy = qy - nb[j * 3 + 1];
            const float dz = qz - nb[j * 3 + 2];
            const float d2 = fmaf(dz, dz, fmaf(dy, dy, dx * dx));
            if (d2 < bd[7]) {
                bd[7] = d2; bi[7] = j;
#pragma unroll
                for (int t = 7; t > 0; --t) {
                    if (bd[t] < bd[t - 1]) {
                        float td = bd[t]; bd[t] = bd[t - 1]; bd[t - 1] = td;
                        int   ti = bi[t]; bi[t] = bi[t - 1]; bi[t - 1] = ti;
                    }
                }
            }
        }
#pragma unroll
        for (int t = 0; t < 8; ++t)
            keys[tid * 8 + t] = ((unsigned long long)__float_as_uint(bd[t]) << 32)
                              | (unsigned int)bi[t];
        __syncthreads();
        for (int k = 2; k <= 2048; k <<= 1) {
            for (int jj = k >> 1; jj > 0; jj >>= 1) {
#pragma unroll
                for (int base = 0; base < 2048; base += 256) {
                    const int i = base + tid;
                    const int partner = i ^ jj;
                    if (partner > i) {
                        const bool asc = ((i & k) == 0);
                        const unsigned long long a = keys[i];
                        const unsigned long long c = keys[partner];
                        if ((a > c) == asc) { keys[i] = c; keys[partner] = a; }
                    }
                }
                __syncthreads();
            }
        }
    }

    if (tid < 32) {
        const int idx = (int)(keys[tid] & 0xFFFFFFFFull);
        g_fidx[qb * 32 + tid] = clampi(idx, 0, N_PTS - 1);
    }
    if (tid == 0) g_q1cnt[qb] = 0;
}

// ---------------------------------------------------------------------------
// Launch 4: fused knn2 + loss (flattened 9-row all-lane walk, R2-proven).
// Final reduction replaced by one pre-scaled float atomicAdd per block into
// out[0] (zeroed in launch 1) — eliminates the final_kernel launch slot.
// ---------------------------------------------------------------------------
__global__ __launch_bounds__(256) void knn2_loss_kernel(
    const float* __restrict__ noisy,
    const float* __restrict__ clean,
    float* __restrict__ out)
{
    __shared__ float2 buf[4][QCAP];    // 3 KB
    __shared__ int    bcnt[4];
    __shared__ float  red[4];
    const int tid  = threadIdx.x;
    const int wv   = tid >> 6;
    const int lane = tid & 63;
    const int g    = blockIdx.x * 4 + wv;
    const int b    = g >> 12;
    const int p    = (g >> 5) & 127;
    const float* nb = noisy + b * (N_PTS * 3);
    const float* cb = clean + b * (N_PTS * 3);

    if (lane == 0) bcnt[wv] = 0;

    const int fid = clampi(g_fidx[g], 0, N_PTS - 1);
    const float fx = nb[fid * 3 + 0];
    const float fy = nb[fid * 3 + 1];
    const float fz = nb[fid * 3 + 2];
    const float fm2x = -2.0f * fx, fm2y = -2.0f * fy, fm2z = -2.0f * fz;
    const float ff = fmaf(fz, fz, fmaf(fy, fy, fx * fx));
    const float taup = TAU2 - ff;

    const int cfx = clampi((int)(fx * NG), 0, NG - 1);
    const int cfy = clampi((int)(fy * NG), 0, NG - 1);
    const int cfz = clampi((int)(fz * NG), 0, NG - 1);
    const int bso = b * (NCELL + 1);
    const int bpo = b * N_PTS;

    // 9 rows (cy,cz); cells cxlo..cxhi are contiguous in the bin-sorted array.
    int s = 0, e = 0;
    if (lane < 9) {
        const int cy = cfy + (lane % 3) - 1;
        const int cz = cfz + (lane / 3) - 1;
        if (cy >= 0 && cy < NG && cz >= 0 && cz < NG) {
            const int cxlo = (cfx > 0) ? cfx - 1 : 0;
            const int cxhi = (cfx < NG - 1) ? cfx + 1 : NG - 1;
            const int rowb = NG * (cy + NG * cz);
            s = g_binstart[bso + cxlo + rowb];
            e = g_binstart[bso + cxhi + rowb + 1];
        }
    }
    const int len = e - s;
    int incl = len;
#pragma unroll
    for (int off = 1; off < 16; off <<= 1) {
        const int nsh = __shfl_up(incl, off);
        if (lane >= off) incl += nsh;
    }
    const int T = __shfl(incl, 8);
    const int pfx = incl - len;          // exclusive prefix for this lane's row

    int rp[9], rs[9];
#pragma unroll
    for (int i = 0; i < 9; ++i) {
        rp[i] = __shfl(pfx, i);
        rs[i] = __shfl(s, i);
    }

    for (int t = lane; t < T; t += 64) {
        int base = rs[0], pref = rp[0];
#pragma unroll
        for (int i = 1; i < 9; ++i) {    // last row with rp[i] <= t (skips len-0 rows)
            const bool gsel = (t >= rp[i]);
            base = gsel ? rs[i] : base;
            pref = gsel ? rp[i] : pref;
        }
        const int k = base + (t - pref);
        const float4 pt = g_cpts[bpo + k];
        const float d2 = fmaf(fm2x, pt.x, fmaf(fm2y, pt.y, fmaf(fm2z, pt.z, pt.w)));
        if (d2 < taup) {
            const int slot = atomicAdd(&bcnt[wv], 1);
            if (slot < QCAP)
                buf[wv][slot] = make_float2(d2, __int_as_float(g_cpidx[bpo + k]));
        }
    }
    __syncthreads();

    // ------- loss: wave butterfly top-4 from the LDS list; exact fallback -------
    const int cnt = bcnt[wv];
    int nn[4];

    if (cnt >= 4 && cnt <= QCAP) {
        unsigned long long e0 = ~0ULL, e1 = ~0ULL;
        if (lane < cnt) {
            const float2 a = buf[wv][lane];
            e0 = packkey(a.x, __float_as_int(a.y));
        }
        if (lane + 64 < cnt) {
            const float2 a = buf[wv][lane + 64];
            e1 = packkey(a.x, __float_as_int(a.y));
        }
        if (e1 < e0) { unsigned long long t = e0; e0 = e1; e1 = t; }

        int c = 0;
#pragma unroll
        for (int r = 0; r < 4; ++r) {
            const unsigned long long h = (c == 0) ? e0 : ((c == 1) ? e1 : ~0ULL);
            unsigned long long m = h;
#pragma unroll
            for (int off = 32; off; off >>= 1) {
                const unsigned long long o = __shfl_xor(m, off);
                if (o < m) m = o;
            }
            if (h == m) c++;
            nn[r] = (int)(m & 0xFFFFFFFFull);
        }
    } else {
        float bd[4]; int bi[4];
#pragma unroll
        for (int t = 0; t < 4; ++t) { bd[t] = BIGF; bi[t] = 0x7fffffff; }
        for (int j = lane; j < N_PTS; j += 64) {
            const float dx = fx - cb[j * 3 + 0];
            const float dy = fy - cb[j * 3 + 1];
            const float dz = fz - cb[j * 3 + 2];
            const float d2 = fmaf(dz, dz, fmaf(dy, dy, dx * dx));
            if (d2 < bd[3]) {
                bd[3] = d2; bi[3] = j;
#pragma unroll
                for (int t = 3; t > 0; --t) {
                    if (bd[t] < bd[t - 1]) {
                        float td = bd[t]; bd[t] = bd[t - 1]; bd[t - 1] = td;
                        int   ti = bi[t]; bi[t] = bi[t - 1]; bi[t - 1] = ti;
                    }
                }
            }
        }
        int cur = 0;
        for (int r = 0; r < 4; ++r) {
            float v  = (cur < 4) ? bd[cur] : BIGF;
            int   vi = (cur < 4) ? bi[cur] : 0x7fffffff;
            int   who = lane;
#pragma unroll
            for (int off = 32; off; off >>= 1) {
                const float v2  = __shfl_down(v, off);
                const int   vi2 = __shfl_down(vi, off);
                const int   w2  = __shfl_down(who, off);
                if (v2 < v || (v2 == v && vi2 < vi)) { v = v2; vi = vi2; who = w2; }
            }
            const int bvi = __shfl(vi, 0);
            const int bwh = __shfl(who, 0);
            nn[r] = bvi;
            if (lane == bwh) cur++;
        }
    }

    float t2 = 0.0f;
    if (lane == 0) {
        const int si = g_sidx[p];
        const float qx = nb[si * 3 + 0], qy = nb[si * 3 + 1], qz = nb[si * 3 + 2];
        const int n0 = clampi(nn[0], 0, N_PTS - 1), n1 = clampi(nn[1], 0, N_PTS - 1);
        const int n2 = clampi(nn[2], 0, N_PTS - 1), n3 = clampi(nn[3], 0, N_PTS - 1);
        const float mx = 0.25f * (cb[n0*3+0] + cb[n1*3+0] + cb[n2*3+0] + cb[n3*3+0]);
        const float my = 0.25f * (cb[n0*3+1] + cb[n1*3+1] + cb[n2*3+1] + cb[n3*3+1]);
        const float mz = 0.25f * (cb[n0*3+2] + cb[n1*3+2] + cb[n2*3+2] + cb[n3*3+2]);

        const float gx = mx - fx, gy = my - fy, gz = mz - fz;
        const float rx = fx - qx, ry = fy - qy, rz = fz - qz;
        const float ex = rx * g_WxS[0] + ry * g_WxS[3] + rz * g_WxS[6] + qx * g_M3[0] + qy * g_M3[3] + qz * g_M3[6];
        const float ey = rx * g_WxS[1] + ry * g_WxS[4] + rz * g_WxS[7] + qx * g_M3[1] + qy * g_M3[4] + qz * g_M3[7];
        const float ez = rx * g_WxS[2] + ry * g_WxS[5] + rz * g_WxS[8] + qx * g_M3[2] + qy * g_M3[5] + qz * g_M3[8];
        const float dx = ex - gx, dy = ey - gy, dz = ez - gz;
        t2 = dx * dx + dy * dy + dz * dz;
    }

    if (lane == 0) red[wv] = t2;
    __syncthreads();
    if (tid == 0)
        atomicAdd(out, ((red[0] + red[1]) + (red[2] + red[3])) * LSCALE);
}

extern "C" void kernel_launch(void* const* d_in, const int* in_sizes, int n_in,
                              void* d_out, int out_size, void* d_ws, size_t ws_size,
                              hipStream_t stream)
{
    (void)d_ws; (void)ws_size; (void)in_sizes; (void)n_in; (void)out_size;

    const float* noisy = (const float*)d_in[0];
    const float* clean = (const float*)d_in[1];
    const float* Wf    = (const float*)d_in[3];
    const float* Wx    = (const float*)d_in[4];
    const float* Wc    = (const float*)d_in[5];

    // 1: hist (40 blocks) + sidx/M3 decode + out=0 (1 block)
    setup_kernel<<<N_B * GB_BLK + 1, 256, 0, stream>>>(clean, d_in[2], Wf, Wx, Wc, (float*)d_out);
    // 2: prefix scan (2 blocks) + knn1 tau-scan (2048 blocks)
    scan_knn1_kernel<<<N_B + 256 * K1SUB, 256, 0, stream>>>(noisy);
    // 3: knn1 merge (256 blocks) + scatter (40 blocks)
    merge_scatter_kernel<<<256 + N_B * GB_BLK, 256, 0, stream>>>(noisy, clean);
    // 4: fused knn2 + loss + atomic finish (2048 blocks)
    knn2_loss_kernel<<<NLOSSB, 256, 0, stream>>>(noisy, clean, (float*)d_out);
}

// Round 7
// 122.917 us; speedup vs baseline: 1.0314x; 1.0314x over previous
//
#include <hip/hip_runtime.h>
#include <hip/hip_bf16.h>

#define N_PTS   40000
#define N_B     2
#define N_P     128
#define N_K     32
#define N_KC    4
#define N_FEAT  128
#define NQ2     (N_B * N_P * N_K)   // 8192
#define BIGF    3.0e38f

#define K1SUB   8
#define K1RANGE (N_PTS / K1SUB)     // 5000
#define QCAP1   512                 // knn1 cap (E[n]=341)
#define LBUF1   320                 // knn1 per-block LDS buffer

#define QCAP    96                  // knn2 per-query cap (E[n]=42)

#define TAU2    4.0e-3f             // (2.2*r4)^2 ; tau=0.0632
#define TAU1    1.6e-2f             // (2.2*r32)^2

#define NG      15                  // grid cells per dim; h=1/15 > tau2
#define NCELL   (NG * NG * NG)      // 3375
#define GB_BLK  20                  // grid-build blocks per batch
#define GB_PER  (N_PTS / GB_BLK)    // 2000 pts per block

#define NLOSSB  2048                // loss blocks (4 waves each = 8192 queries)
#define LSCALE  (50.0f / 8192.0f)

// Globals (zero-init at load; consumers reset their own counters each call).
__device__ int    g_sidx[N_P];
__device__ int    g_fidx[NQ2];
__device__ int    g_q1cnt[256];
__device__ unsigned long long g_q1list[256 * QCAP1];   // 1 MB
__device__ int    g_bincnt[N_B * NCELL];               // histogram (reset by scan)
__device__ int    g_binstart[N_B * (NCELL + 1)];
__device__ int    g_cursor[N_B * NCELL];               // scatter cursors
__device__ float4 g_cpts[N_B * N_PTS];                 // bin-sorted clean pts (x,y,z,pp)
__device__ int    g_cpidx[N_B * N_PTS];                // original indices
__device__ float  g_M3[9];
__device__ float  g_WxS[9];
// Fence-free finisher state (32-way spread; R5 lesson: same-address atomics
// cost ~30cy serialized -> spread them). Reset by the finisher each call.
__device__ float  g_lp32[32];
__device__ int    g_gdone[32];
__device__ int    g_fdone;

__device__ __forceinline__ int clampi(int v, int lo, int hi) { return v < lo ? lo : (v > hi ? hi : v); }

__device__ __forceinline__ unsigned long long packkey(float d, int idx)
{
    unsigned int u = __float_as_uint(d);
    u ^= (u >> 31) ? 0xFFFFFFFFu : 0x80000000u;
    return ((unsigned long long)u << 32) | (unsigned int)idx;
}

__device__ __forceinline__ int cell_of(float x, float y, float z)
{
    const int cx = clampi((int)(x * NG), 0, NG - 1);
    const int cy = clampi((int)(y * NG), 0, NG - 1);
    const int cz = clampi((int)(z * NG), 0, NG - 1);
    return cx + NG * (cy + NG * cz);
}

// ---------------------------------------------------------------------------
// Launch 1: grid histogram (blocks 0..39) + sidx decode / M3 / WxS (block 40).
// R1 lesson: no per-block __threadfence (whole-L2 wb/inv storm).
// ---------------------------------------------------------------------------
__global__ __launch_bounds__(256) void setup_kernel(
    const float* __restrict__ clean,
    const void*  __restrict__ sidx_raw,
    const float* __restrict__ Wf,
    const float* __restrict__ Wx,
    const float* __restrict__ Wc)
{
    __shared__ int hist[NCELL];     // 13.5 KB
    __shared__ int flags[4];
    const int blk = blockIdx.x;
    const int tid = threadIdx.x;

    if (blk < N_B * GB_BLK) {
        // ------- grid histogram (verbatim) -------
        const int bb = blk / GB_BLK;
        const int sb = blk % GB_BLK;
        const float* cb = clean + bb * (N_PTS * 3);

        for (int i = tid; i < NCELL; i += 256) hist[i] = 0;
        __syncthreads();

        const int j0 = sb * GB_PER;
        for (int j = j0 + tid; j < j0 + GB_PER; j += 256) {
            const float x = cb[j * 3 + 0], y = cb[j * 3 + 1], z = cb[j * 3 + 2];
            atomicAdd(&hist[cell_of(x, y, z)], 1);
        }
        __syncthreads();

        for (int i = tid; i < NCELL; i += 256) {
            const int v = hist[i];
            if (v) atomicAdd(&g_bincnt[bb * NCELL + i], v);   // no-return: pipelines freely
        }
    } else {
        // ------- hoisted M3/Wx + sidx dtype-vote decode (verbatim) -------
        if (tid < 9) {
            const int d = tid / 3, e = tid % 3;
            float acc = 0.0f;
            for (int f0 = 0; f0 < N_FEAT; ++f0)
                acc += Wf[d * N_FEAT + f0] * Wc[f0 * 3 + e];
            g_M3[tid]  = acc;
            g_WxS[tid] = Wx[tid];
        }
        if (tid == 0) { flags[0] = 1; flags[1] = 1; flags[2] = 1; flags[3] = 1; }
        __syncthreads();
        const int*       p32 = (const int*)sidx_raw;
        const long long* p64 = (const long long*)sidx_raw;
        const float*     pf  = (const float*)sidx_raw;
        if (tid < 128) {
            const int       v32 = p32[tid];
            const long long v64 = p64[tid];
            const float     vf  = pf[tid];
            if (!(v32 >= 0 && v32 < N_PTS)) atomicAnd(&flags[0], 0);
            if ((tid & 1) && v32 != 0)      atomicAnd(&flags[1], 0);
            if (!(v64 >= 0 && v64 < N_PTS)) atomicAnd(&flags[2], 0);
            if (!(vf >= 0.0f && vf < (float)N_PTS && vf == floorf(vf))) atomicAnd(&flags[3], 0);
        }
        __syncthreads();
        if (tid < 128) {
            int si;
            if (flags[0] && !(flags[1] && flags[2])) si = p32[tid];
            else if (flags[2])                       si = (int)p64[tid];
            else if (flags[3])                       si = (int)(pf[tid] + 0.5f);
            else                                     si = 0;
            g_sidx[tid] = clampi(si, 0, N_PTS - 1);
        }
    }
}

// ---------------------------------------------------------------------------
// Launch 2: grid prefix scan (blocks 0..1) + knn1 tau-scan (blocks 2..2049).
// NEW: knn1 scan processes 4 points/thread via 3 aligned float4 loads
// (block base sub*60000B and 48B quad stride are both 16B-aligned). Same
// fmaf chains -> bit-identical d2 keys; candidate ORDER differs but the
// merge sorts by unique packed key, so the final top-32 is identical.
// ---------------------------------------------------------------------------
__global__ __launch_bounds__(256) void scan_knn1_kernel(
    const float* __restrict__ noisy)
{
    __shared__ unsigned long long buf[LBUF1];  // knn1 branch
    __shared__ int lcnt;
    __shared__ int base_s;
    __shared__ int wsum[4], woff[4];           // scan branch
    const int blk = blockIdx.x;
    const int tid = threadIdx.x;

    if (blk < N_B) {
        // ------- prefix scan + cursor init + bincnt reset (verbatim) -------
        const int bb   = blk;
        const int lane = tid & 63, wv = tid >> 6;

        int lvals[14];
        int lsum = 0;
#pragma unroll
        for (int t = 0; t < 14; ++t) {
            const int idx = tid * 14 + t;
            lvals[t] = (idx < NCELL) ? g_bincnt[bb * NCELL + idx] : 0;
            lsum += lvals[t];
        }
        int v = lsum;
#pragma unroll
        for (int off = 1; off < 64; off <<= 1) {
            const int n = __shfl_up(v, off);
            if (lane >= off) v += n;
        }
        if (lane == 63) wsum[wv] = v;
        __syncthreads();
        if (tid == 0) { int r = 0; for (int w = 0; w < 4; ++w) { woff[w] = r; r += wsum[w]; } }
        __syncthreads();

        int run = woff[wv] + (v - lsum);    // exclusive prefix for this thread's chunk
#pragma unroll
        for (int t = 0; t < 14; ++t) {
            const int idx = tid * 14 + t;
            if (idx < NCELL) {
                g_binstart[bb * (NCELL + 1) + idx] = run;
                g_cursor[bb * NCELL + idx] = run;
                g_bincnt[bb * NCELL + idx] = 0;    // reset for next call
                run += lvals[t];
            }
        }
        if (tid == 0) g_binstart[bb * (NCELL + 1) + NCELL] = N_PTS;
    } else {
        // ------- knn1 LDS-buffered tau-append (quad-vectorized loads) -------
        const int idx = blk - N_B;
        const int qb  = idx & 255;
        const int sub = idx >> 8;
        const int b   = qb >> 7;
        const int p   = qb & 127;
        const float* nb = noisy + b * (N_PTS * 3);

        if (tid == 0) lcnt = 0;
        const int si = g_sidx[p];
        const float qx = nb[si * 3 + 0];
        const float qy = nb[si * 3 + 1];
        const float qz = nb[si * 3 + 2];
        __syncthreads();

        const int jbeg = sub * K1RANGE;
        const float4* p4 = (const float4*)(nb + jbeg * 3);   // 16B-aligned
        const int nq = K1RANGE / 4;                          // 1250 quads
        for (int q = tid; q < nq; q += 256) {
            const float4 a = p4[q * 3 + 0];
            const float4 c = p4[q * 3 + 1];
            const float4 d = p4[q * 3 + 2];
            const int j = jbeg + q * 4;
            {
                const float dx = qx - a.x, dy = qy - a.y, dz = qz - a.z;
                const float d2 = fmaf(dz, dz, fmaf(dy, dy, dx * dx));
                if (d2 < TAU1) {
                    const int s1 = atomicAdd(&lcnt, 1);
                    if (s1 < LBUF1)
                        buf[s1] = ((unsigned long long)__float_as_uint(d2) << 32) | (unsigned int)(j + 0);
                }
            }
            {
                const float dx = qx - a.w, dy = qy - c.x, dz = qz - c.y;
                const float d2 = fmaf(dz, dz, fmaf(dy, dy, dx * dx));
                if (d2 < TAU1) {
                    const int s1 = atomicAdd(&lcnt, 1);
                    if (s1 < LBUF1)
                        buf[s1] = ((unsigned long long)__float_as_uint(d2) << 32) | (unsigned int)(j + 1);
                }
            }
            {
                const float dx = qx - c.z, dy = qy - c.w, dz = qz - d.x;
                const float d2 = fmaf(dz, dz, fmaf(dy, dy, dx * dx));
                if (d2 < TAU1) {
                    const int s1 = atomicAdd(&lcnt, 1);
                    if (s1 < LBUF1)
                        buf[s1] = ((unsigned long long)__float_as_uint(d2) << 32) | (unsigned int)(j + 2);
                }
            }
            {
                const float dx = qx - d.y, dy = qy - d.z, dz = qz - d.w;
                const float d2 = fmaf(dz, dz, fmaf(dy, dy, dx * dx));
                if (d2 < TAU1) {
                    const int s1 = atomicAdd(&lcnt, 1);
                    if (s1 < LBUF1)
                        buf[s1] = ((unsigned long long)__float_as_uint(d2) << 32) | (unsigned int)(j + 3);
                }
            }
        }
        __syncthreads();

        const int cnt = lcnt;
        if (tid == 0) {
            const int add = (cnt <= LBUF1) ? cnt : (QCAP1 + 1000);
            base_s = atomicAdd(&g_q1cnt[qb], add);
        }
        __syncthreads();

        const int base = base_s;
        const int n = (cnt < LBUF1) ? cnt : LBUF1;
        for (int i = tid; i < n; i += 256) {
            const int o = base + i;
            if (o < QCAP1) g_q1list[qb * QCAP1 + o] = buf[i];
        }
    }
}

// ---------------------------------------------------------------------------
// Launch 3: knn1 merge (blocks 0..255) + grid scatter (blocks 256..295).
// ---------------------------------------------------------------------------
__global__ __launch_bounds__(256) void merge_scatter_kernel(
    const float* __restrict__ noisy,
    const float* __restrict__ clean)
{
    __shared__ unsigned long long keys[2048];
    const int blk = blockIdx.x;
    const int tid = threadIdx.x;

    if (blk >= 256) {
        // ------- scatter via low-contention cursor atomics (verbatim) -------
        const int idx = blk - 256;
        const int bb  = idx / GB_BLK;
        const int sb  = idx % GB_BLK;
        const float* cb = clean + bb * (N_PTS * 3);

        const int j0 = sb * GB_PER;
        for (int j = j0 + tid; j < j0 + GB_PER; j += 256) {
            const float x = cb[j * 3 + 0], y = cb[j * 3 + 1], z = cb[j * 3 + 2];
            const int c = cell_of(x, y, z);
            const int pos = atomicAdd(&g_cursor[bb * NCELL + c], 1);
            const float pp = fmaf(z, z, fmaf(y, y, x * x));
            g_cpts[bb * N_PTS + pos]  = make_float4(x, y, z, pp);
            g_cpidx[bb * N_PTS + pos] = j;
        }
        return;
    }

    // ------- knn1 merge: 512-key bitonic; inline exact fallback (verbatim) -------
    const int qb  = blk;
    const int cnt = g_q1cnt[qb];

    if (cnt >= 32 && cnt <= QCAP1) {
        for (int i = tid; i < QCAP1; i += 256)
            keys[i] = (i < cnt) ? g_q1list[qb * QCAP1 + i] : ~0ULL;
        __syncthreads();
        for (int k = 2; k <= QCAP1; k <<= 1) {
            for (int jj = k >> 1; jj > 0; jj >>= 1) {
                const int idx = tid;
                const int i = ((idx & ~(jj - 1)) << 1) | (idx & (jj - 1));
                const int partner = i | jj;
                const bool asc = ((i & k) == 0);
                const unsigned long long a = keys[i];
                const unsigned long long c = keys[partner];
                if ((a > c) == asc) { keys[i] = c; keys[partner] = a; }
                __syncthreads();
            }
        }
    } else {
        const int b = qb >> 7;
        const float* nb = noisy + b * (N_PTS * 3);
        const int si = g_sidx[qb & 127];
        const float qx = nb[si * 3 + 0];
        const float qy = nb[si * 3 + 1];
        const float qz = nb[si * 3 + 2];

        float bd[8]; int bi[8];
#pragma unroll
        for (int i = 0; i < 8; ++i) { bd[i] = BIGF; bi[i] = 0x7fffffff; }
        for (int j = tid; j < N_PTS; j += 256) {
            const float dx = qx - nb[j * 3 + 0];
            const float dy = qy - nb[j * 3 + 1];
            const float dz = qz - nb[j * 3 + 2];
            const float d2 = fmaf(dz, dz, fmaf(dy, dy, dx * dx));
            if (d2 < bd[7]) {
                bd[7] = d2; bi[7] = j;
#pragma unroll
                for (int t = 7; t > 0; --t) {
                    if (bd[t] < bd[t - 1]) {
                        float td = bd[t]; bd[t] = bd[t - 1]; bd[t - 1] = td;
                        int   ti = bi[t]; bi[t] = bi[t - 1]; bi[t - 1] = ti;
                    }
                }
            }
        }
#pragma unroll
        for (int t = 0; t < 8; ++t)
            keys[tid * 8 + t] = ((unsigned long long)__float_as_uint(bd[t]) << 32)
                              | (unsigned int)bi[t];
        __syncthreads();
        for (int k = 2; k <= 2048; k <<= 1) {
            for (int jj = k >> 1; jj > 0; jj >>= 1) {
#pragma unroll
                for (int base = 0; base < 2048; base += 256) {
                    const int i = base + tid;
                    const int partner = i ^ jj;
                    if (partner > i) {
                        const bool asc = ((i & k) == 0);
                        const unsigned long long a = keys[i];
                        const unsigned long long c = keys[partner];
                        if ((a > c) == asc) { keys[i] = c; keys[partner] = a; }
                    }
                }
                __syncthreads();
            }
        }
    }

    if (tid < 32) {
        const int idx = (int)(keys[tid] & 0xFFFFFFFFull);
        g_fidx[qb * 32 + tid] = clampi(idx, 0, N_PTS - 1);
    }
    if (tid == 0) g_q1cnt[qb] = 0;
}

// ---------------------------------------------------------------------------
// Launch 4: fused knn2 + loss (flattened 9-row all-lane walk, R2-proven)
// + fence-free hierarchical atomic finisher (replaces final launch).
// Ordering: each atomic's RETURN VALUE is consumed (asm sink / compare)
// before the next atomic issues -> s_waitcnt vmcnt drains, so the RMW is
// complete at the coherence point. No __threadfence (R1 lesson). Atomics
// spread 32-way (R5 lesson: same-address RMW ~30cy serialized).
// ---------------------------------------------------------------------------
__global__ __launch_bounds__(256) void knn2_loss_kernel(
    const float* __restrict__ noisy,
    const float* __restrict__ clean,
    float* __restrict__ out)
{
    __shared__ float2 buf[4][QCAP];    // 3 KB
    __shared__ int    bcnt[4];
    __shared__ float  red[4];
    __shared__ int    isfin;
    const int tid  = threadIdx.x;
    const int wv   = tid >> 6;
    const int lane = tid & 63;
    const int g    = blockIdx.x * 4 + wv;
    const int b    = g >> 12;
    const int p    = (g >> 5) & 127;
    const float* nb = noisy + b * (N_PTS * 3);
    const float* cb = clean + b * (N_PTS * 3);

    if (tid == 0) isfin = 0;
    if (lane == 0) bcnt[wv] = 0;

    const int fid = clampi(g_fidx[g], 0, N_PTS - 1);
    const float fx = nb[fid * 3 + 0];
    const float fy = nb[fid * 3 + 1];
    const float fz = nb[fid * 3 + 2];
    const float fm2x = -2.0f * fx, fm2y = -2.0f * fy, fm2z = -2.0f * fz;
    const float ff = fmaf(fz, fz, fmaf(fy, fy, fx * fx));
    const float taup = TAU2 - ff;

    const int cfx = clampi((int)(fx * NG), 0, NG - 1);
    const int cfy = clampi((int)(fy * NG), 0, NG - 1);
    const int cfz = clampi((int)(fz * NG), 0, NG - 1);
    const int bso = b * (NCELL + 1);
    const int bpo = b * N_PTS;

    // 9 rows (cy,cz); cells cxlo..cxhi are contiguous in the bin-sorted array.
    int s = 0, e = 0;
    if (lane < 9) {
        const int cy = cfy + (lane % 3) - 1;
        const int cz = cfz + (lane / 3) - 1;
        if (cy >= 0 && cy < NG && cz >= 0 && cz < NG) {
            const int cxlo = (cfx > 0) ? cfx - 1 : 0;
            const int cxhi = (cfx < NG - 1) ? cfx + 1 : NG - 1;
            const int rowb = NG * (cy + NG * cz);
            s = g_binstart[bso + cxlo + rowb];
            e = g_binstart[bso + cxhi + rowb + 1];
        }
    }
    const int len = e - s;
    int incl = len;
#pragma unroll
    for (int off = 1; off < 16; off <<= 1) {
        const int nsh = __shfl_up(incl, off);
        if (lane >= off) incl += nsh;
    }
    const int T = __shfl(incl, 8);
    const int pfx = incl - len;          // exclusive prefix for this lane's row

    int rp[9], rs[9];
#pragma unroll
    for (int i = 0; i < 9; ++i) {
        rp[i] = __shfl(pfx, i);
        rs[i] = __shfl(s, i);
    }

    for (int t = lane; t < T; t += 64) {
        int base = rs[0], pref = rp[0];
#pragma unroll
        for (int i = 1; i < 9; ++i) {    // last row with rp[i] <= t (skips len-0 rows)
            const bool gsel = (t >= rp[i]);
            base = gsel ? rs[i] : base;
            pref = gsel ? rp[i] : pref;
        }
        const int k = base + (t - pref);
        const float4 pt = g_cpts[bpo + k];
        const float d2 = fmaf(fm2x, pt.x, fmaf(fm2y, pt.y, fmaf(fm2z, pt.z, pt.w)));
        if (d2 < taup) {
            const int slot = atomicAdd(&bcnt[wv], 1);
            if (slot < QCAP)
                buf[wv][slot] = make_float2(d2, __int_as_float(g_cpidx[bpo + k]));
        }
    }
    __syncthreads();

    // ------- loss: wave butterfly top-4 from the LDS list; exact fallback -------
    const int cnt = bcnt[wv];
    int nn[4];

    if (cnt >= 4 && cnt <= QCAP) {
        unsigned long long e0 = ~0ULL, e1 = ~0ULL;
        if (lane < cnt) {
            const float2 a = buf[wv][lane];
            e0 = packkey(a.x, __float_as_int(a.y));
        }
        if (lane + 64 < cnt) {
            const float2 a = buf[wv][lane + 64];
            e1 = packkey(a.x, __float_as_int(a.y));
        }
        if (e1 < e0) { unsigned long long t = e0; e0 = e1; e1 = t; }

        int c = 0;
#pragma unroll
        for (int r = 0; r < 4; ++r) {
            const unsigned long long h = (c == 0) ? e0 : ((c == 1) ? e1 : ~0ULL);
            unsigned long long m = h;
#pragma unroll
            for (int off = 32; off; off >>= 1) {
                const unsigned long long o = __shfl_xor(m, off);
                if (o < m) m = o;
            }
            if (h == m) c++;
            nn[r] = (int)(m & 0xFFFFFFFFull);
        }
    } else {
        float bd[4]; int bi[4];
#pragma unroll
        for (int t = 0; t < 4; ++t) { bd[t] = BIGF; bi[t] = 0x7fffffff; }
        for (int j = lane; j < N_PTS; j += 64) {
            const float dx = fx - cb[j * 3 + 0];
            const float dy = fy - cb[j * 3 + 1];
            const float dz = fz - cb[j * 3 + 2];
            const float d2 = fmaf(dz, dz, fmaf(dy, dy, dx * dx));
            if (d2 < bd[3]) {
                bd[3] = d2; bi[3] = j;
#pragma unroll
                for (int t = 3; t > 0; --t) {
                    if (bd[t] < bd[t - 1]) {
                        float td = bd[t]; bd[t] = bd[t - 1]; bd[t - 1] = td;
                        int   ti = bi[t]; bi[t] = bi[t - 1]; bi[t - 1] = ti;
                    }
                }
            }
        }
        int cur = 0;
        for (int r = 0; r < 4; ++r) {
            float v  = (cur < 4) ? bd[cur] : BIGF;
            int   vi = (cur < 4) ? bi[cur] : 0x7fffffff;
            int   who = lane;
#pragma unroll
            for (int off = 32; off; off >>= 1) {
                const float v2  = __shfl_down(v, off);
                const int   vi2 = __shfl_down(vi, off);
                const int   w2  = __shfl_down(who, off);
                if (v2 < v || (v2 == v && vi2 < vi)) { v = v2; vi = vi2; who = w2; }
            }
            const int bvi = __shfl(vi, 0);
            const int bwh = __shfl(who, 0);
            nn[r] = bvi;
            if (lane == bwh) cur++;
        }
    }

    float t2 = 0.0f;
    if (lane == 0) {
        const int si = g_sidx[p];
        const float qx = nb[si * 3 + 0], qy = nb[si * 3 + 1], qz = nb[si * 3 + 2];
        const int n0 = clampi(nn[0], 0, N_PTS - 1), n1 = clampi(nn[1], 0, N_PTS - 1);
        const int n2 = clampi(nn[2], 0, N_PTS - 1), n3 = clampi(nn[3], 0, N_PTS - 1);
        const float mx = 0.25f * (cb[n0*3+0] + cb[n1*3+0] + cb[n2*3+0] + cb[n3*3+0]);
        const float my = 0.25f * (cb[n0*3+1] + cb[n1*3+1] + cb[n2*3+1] + cb[n3*3+1]);
        const float mz = 0.25f * (cb[n0*3+2] + cb[n1*3+2] + cb[n2*3+2] + cb[n3*3+2]);

        const float gx = mx - fx, gy = my - fy, gz = mz - fz;
        const float rx = fx - qx, ry = fy - qy, rz = fz - qz;
        const float ex = rx * g_WxS[0] + ry * g_WxS[3] + rz * g_WxS[6] + qx * g_M3[0] + qy * g_M3[3] + qz * g_M3[6];
        const float ey = rx * g_WxS[1] + ry * g_WxS[4] + rz * g_WxS[7] + qx * g_M3[1] + qy * g_M3[4] + qz * g_M3[7];
        const float ez = rx * g_WxS[2] + ry * g_WxS[5] + rz * g_WxS[8] + qx * g_M3[2] + qy * g_M3[5] + qz * g_M3[8];
        const float dx = ex - gx, dy = ey - gy, dz = ez - gz;
        t2 = dx * dx + dy * dy + dz * dz;
    }

    if (lane == 0) red[wv] = t2;
    __syncthreads();

    // ------- fence-free finisher choreography (tid 0 only) -------
    if (tid == 0) {
        const float part = ((red[0] + red[1]) + (red[2] + red[3])) * LSCALE;
        const int sgrp = blockIdx.x & 31;
        const float old = atomicAdd(&g_lp32[sgrp], part);
        asm volatile("" :: "v"(old) : "memory");         // drain: partial applied
        const int gd = atomicAdd(&g_gdone[sgrp], 1);     // compare = forced use
        if (gd == 63) {                                  // last of 64 in group
            const int fd = atomicAdd(&g_fdone, 1);       // compare = forced use
            if (fd == 31) isfin = 1;                     // unique global finisher
        }
    }
    __syncthreads();

    if (isfin && tid < 64) {
        float v = (tid < 32) ? atomicAdd(&g_lp32[tid], 0.0f) : 0.0f;  // coherent read
#pragma unroll
        for (int off = 16; off; off >>= 1) v += __shfl_down(v, off);
        if (tid < 32) { g_lp32[tid] = 0.0f; g_gdone[tid] = 0; }       // reset for next call
        if (tid == 0) { out[0] = v; g_fdone = 0; }
    }
}

extern "C" void kernel_launch(void* const* d_in, const int* in_sizes, int n_in,
                              void* d_out, int out_size, void* d_ws, size_t ws_size,
                              hipStream_t stream)
{
    (void)d_ws; (void)ws_size; (void)in_sizes; (void)n_in; (void)out_size;

    const float* noisy = (const float*)d_in[0];
    const float* clean = (const float*)d_in[1];
    const float* Wf    = (const float*)d_in[3];
    const float* Wx    = (const float*)d_in[4];
    const float* Wc    = (const float*)d_in[5];

    // 1: hist (40 blocks) + sidx/M3 decode (1 block)
    setup_kernel<<<N_B * GB_BLK + 1, 256, 0, stream>>>(clean, d_in[2], Wf, Wx, Wc);
    // 2: prefix scan (2 blocks) + knn1 tau-scan, quad-vectorized (2048 blocks)
    scan_knn1_kernel<<<N_B + 256 * K1SUB, 256, 0, stream>>>(noisy);
    // 3: knn1 merge (256 blocks) + scatter (40 blocks)
    merge_scatter_kernel<<<256 + N_B * GB_BLK, 256, 0, stream>>>(noisy, clean);
    // 4: fused knn2 + loss + fence-free finisher (2048 blocks)
    knn2_loss_kernel<<<NLOSSB, 256, 0, stream>>>(noisy, clean, (float*)d_out);
}

// Round 8
// 103.615 us; speedup vs baseline: 1.2236x; 1.1863x over previous
//
#include <hip/hip_runtime.h>
#include <hip/hip_bf16.h>

#define N_PTS   40000
#define N_B     2
#define N_P     128
#define N_K     32
#define N_KC    4
#define N_FEAT  128
#define NQ2     (N_B * N_P * N_K)   // 8192
#define BIGF    3.0e38f

#define K1SUB   8
#define K1RANGE (N_PTS / K1SUB)     // 5000
#define QCAP1   512                 // knn1 cap (E[n]=341)
#define LBUF1   320                 // knn1 per-block LDS buffer

#define QCAP    96                  // knn2 per-query cap (E[n]=42)

#define TAU2    4.0e-3f             // (2.2*r4)^2 ; tau=0.0632
#define TAU1    1.6e-2f             // (2.2*r32)^2

#define NG      15                  // grid cells per dim; h=1/15 > tau2
#define NCELL   (NG * NG * NG)      // 3375
#define GB_BLK  20                  // grid-build blocks per batch
#define GB_PER  (N_PTS / GB_BLK)    // 2000 pts per block

#define NLOSSB  2048                // loss blocks (4 waves each = 8192 queries)

// Globals (zero-init at load; consumers reset their own counters each call).
__device__ int    g_sidx[N_P];
__device__ int    g_fidx[NQ2];
__device__ int    g_q1cnt[256];
__device__ unsigned long long g_q1list[256 * QCAP1];   // 1 MB
__device__ int    g_bincnt[N_B * NCELL];               // histogram (reset by scan)
__device__ int    g_binstart[N_B * (NCELL + 1)];
__device__ int    g_cursor[N_B * NCELL];               // scatter cursors
__device__ float4 g_cpts[N_B * N_PTS];                 // bin-sorted clean pts (x,y,z,pp)
__device__ int    g_cpidx[N_B * N_PTS];                // original indices
__device__ float  g_lploss[NLOSSB];                    // per-block partials
__device__ float  g_M3[9];
__device__ float  g_WxS[9];

__device__ __forceinline__ int clampi(int v, int lo, int hi) { return v < lo ? lo : (v > hi ? hi : v); }

__device__ __forceinline__ unsigned long long packkey(float d, int idx)
{
    unsigned int u = __float_as_uint(d);
    u ^= (u >> 31) ? 0xFFFFFFFFu : 0x80000000u;
    return ((unsigned long long)u << 32) | (unsigned int)idx;
}

__device__ __forceinline__ int cell_of(float x, float y, float z)
{
    const int cx = clampi((int)(x * NG), 0, NG - 1);
    const int cy = clampi((int)(y * NG), 0, NG - 1);
    const int cz = clampi((int)(z * NG), 0, NG - 1);
    return cx + NG * (cy + NG * cz);
}

// ---------------------------------------------------------------------------
// Launch 1: grid histogram (blocks 0..39) + sidx decode / M3 / WxS (block 40).
// R1 lesson: no in-kernel cross-block finishers (per-block fence = L2 storm).
// R5/R6 lesson: no atomic-funnel finishers either (~+17-25 us at 2048 blocks).
// ---------------------------------------------------------------------------
__global__ __launch_bounds__(256) void setup_kernel(
    const float* __restrict__ clean,
    const void*  __restrict__ sidx_raw,
    const float* __restrict__ Wf,
    const float* __restrict__ Wx,
    const float* __restrict__ Wc)
{
    __shared__ int hist[NCELL];     // 13.5 KB
    __shared__ int flags[4];
    const int blk = blockIdx.x;
    const int tid = threadIdx.x;

    if (blk < N_B * GB_BLK) {
        // ------- grid histogram (verbatim) -------
        const int bb = blk / GB_BLK;
        const int sb = blk % GB_BLK;
        const float* cb = clean + bb * (N_PTS * 3);

        for (int i = tid; i < NCELL; i += 256) hist[i] = 0;
        __syncthreads();

        const int j0 = sb * GB_PER;
        for (int j = j0 + tid; j < j0 + GB_PER; j += 256) {
            const float x = cb[j * 3 + 0], y = cb[j * 3 + 1], z = cb[j * 3 + 2];
            atomicAdd(&hist[cell_of(x, y, z)], 1);
        }
        __syncthreads();

        for (int i = tid; i < NCELL; i += 256) {
            const int v = hist[i];
            if (v) atomicAdd(&g_bincnt[bb * NCELL + i], v);   // no-return: pipelines freely
        }
    } else {
        // ------- hoisted M3/Wx + sidx dtype-vote decode (verbatim) -------
        if (tid < 9) {
            const int d = tid / 3, e = tid % 3;
            float acc = 0.0f;
            for (int f0 = 0; f0 < N_FEAT; ++f0)
                acc += Wf[d * N_FEAT + f0] * Wc[f0 * 3 + e];
            g_M3[tid]  = acc;
            g_WxS[tid] = Wx[tid];
        }
        if (tid == 0) { flags[0] = 1; flags[1] = 1; flags[2] = 1; flags[3] = 1; }
        __syncthreads();
        const int*       p32 = (const int*)sidx_raw;
        const long long* p64 = (const long long*)sidx_raw;
        const float*     pf  = (const float*)sidx_raw;
        if (tid < 128) {
            const int       v32 = p32[tid];
            const long long v64 = p64[tid];
            const float     vf  = pf[tid];
            if (!(v32 >= 0 && v32 < N_PTS)) atomicAnd(&flags[0], 0);
            if ((tid & 1) && v32 != 0)      atomicAnd(&flags[1], 0);
            if (!(v64 >= 0 && v64 < N_PTS)) atomicAnd(&flags[2], 0);
            if (!(vf >= 0.0f && vf < (float)N_PTS && vf == floorf(vf))) atomicAnd(&flags[3], 0);
        }
        __syncthreads();
        if (tid < 128) {
            int si;
            if (flags[0] && !(flags[1] && flags[2])) si = p32[tid];
            else if (flags[2])                       si = (int)p64[tid];
            else if (flags[3])                       si = (int)(pf[tid] + 0.5f);
            else                                     si = 0;
            g_sidx[tid] = clampi(si, 0, N_PTS - 1);
        }
    }
}

// ---------------------------------------------------------------------------
// Launch 2: grid prefix scan (blocks 0..1) + knn1 tau-scan (blocks 2..2049).
// ONLY change vs the 107.8us champion: knn1 scan processes 4 points/thread
// via 3 aligned float4 loads (block base sub*60000B, quad stride 48B, both
// 16B-aligned). Same fmaf chains -> bit-identical d2 keys; candidate ORDER
// differs but the merge sorts unique packed keys -> identical top-32.
// ---------------------------------------------------------------------------
__global__ __launch_bounds__(256) void scan_knn1_kernel(
    const float* __restrict__ noisy)
{
    __shared__ unsigned long long buf[LBUF1];  // knn1 branch
    __shared__ int lcnt;
    __shared__ int base_s;
    __shared__ int wsum[4], woff[4];           // scan branch
    const int blk = blockIdx.x;
    const int tid = threadIdx.x;

    if (blk < N_B) {
        // ------- prefix scan + cursor init + bincnt reset (verbatim) -------
        const int bb   = blk;
        const int lane = tid & 63, wv = tid >> 6;

        int lvals[14];
        int lsum = 0;
#pragma unroll
        for (int t = 0; t < 14; ++t) {
            const int idx = tid * 14 + t;
            lvals[t] = (idx < NCELL) ? g_bincnt[bb * NCELL + idx] : 0;
            lsum += lvals[t];
        }
        int v = lsum;
#pragma unroll
        for (int off = 1; off < 64; off <<= 1) {
            const int n = __shfl_up(v, off);
            if (lane >= off) v += n;
        }
        if (lane == 63) wsum[wv] = v;
        __syncthreads();
        if (tid == 0) { int r = 0; for (int w = 0; w < 4; ++w) { woff[w] = r; r += wsum[w]; } }
        __syncthreads();

        int run = woff[wv] + (v - lsum);    // exclusive prefix for this thread's chunk
#pragma unroll
        for (int t = 0; t < 14; ++t) {
            const int idx = tid * 14 + t;
            if (idx < NCELL) {
                g_binstart[bb * (NCELL + 1) + idx] = run;
                g_cursor[bb * NCELL + idx] = run;
                g_bincnt[bb * NCELL + idx] = 0;    // reset for next call
                run += lvals[t];
            }
        }
        if (tid == 0) g_binstart[bb * (NCELL + 1) + NCELL] = N_PTS;
    } else {
        // ------- knn1 LDS-buffered tau-append (quad-vectorized loads) -------
        const int idx = blk - N_B;
        const int qb  = idx & 255;
        const int sub = idx >> 8;
        const int b   = qb >> 7;
        const int p   = qb & 127;
        const float* nb = noisy + b * (N_PTS * 3);

        if (tid == 0) lcnt = 0;
        const int si = g_sidx[p];
        const float qx = nb[si * 3 + 0];
        const float qy = nb[si * 3 + 1];
        const float qz = nb[si * 3 + 2];
        __syncthreads();

        const int jbeg = sub * K1RANGE;
        const float4* p4 = (const float4*)(nb + jbeg * 3);   // 16B-aligned
        const int nq = K1RANGE / 4;                          // 1250 quads
        for (int q = tid; q < nq; q += 256) {
            const float4 a = p4[q * 3 + 0];
            const float4 c = p4[q * 3 + 1];
            const float4 d = p4[q * 3 + 2];
            const int j = jbeg + q * 4;
            {
                const float dx = qx - a.x, dy = qy - a.y, dz = qz - a.z;
                const float d2 = fmaf(dz, dz, fmaf(dy, dy, dx * dx));
                if (d2 < TAU1) {
                    const int s1 = atomicAdd(&lcnt, 1);
                    if (s1 < LBUF1)
                        buf[s1] = ((unsigned long long)__float_as_uint(d2) << 32) | (unsigned int)(j + 0);
                }
            }
            {
                const float dx = qx - a.w, dy = qy - c.x, dz = qz - c.y;
                const float d2 = fmaf(dz, dz, fmaf(dy, dy, dx * dx));
                if (d2 < TAU1) {
                    const int s1 = atomicAdd(&lcnt, 1);
                    if (s1 < LBUF1)
                        buf[s1] = ((unsigned long long)__float_as_uint(d2) << 32) | (unsigned int)(j + 1);
                }
            }
            {
                const float dx = qx - c.z, dy = qy - c.w, dz = qz - d.x;
                const float d2 = fmaf(dz, dz, fmaf(dy, dy, dx * dx));
                if (d2 < TAU1) {
                    const int s1 = atomicAdd(&lcnt, 1);
                    if (s1 < LBUF1)
                        buf[s1] = ((unsigned long long)__float_as_uint(d2) << 32) | (unsigned int)(j + 2);
                }
            }
            {
                const float dx = qx - d.y, dy = qy - d.z, dz = qz - d.w;
                const float d2 = fmaf(dz, dz, fmaf(dy, dy, dx * dx));
                if (d2 < TAU1) {
                    const int s1 = atomicAdd(&lcnt, 1);
                    if (s1 < LBUF1)
                        buf[s1] = ((unsigned long long)__float_as_uint(d2) << 32) | (unsigned int)(j + 3);
                }
            }
        }
        __syncthreads();

        const int cnt = lcnt;
        if (tid == 0) {
            const int add = (cnt <= LBUF1) ? cnt : (QCAP1 + 1000);
            base_s = atomicAdd(&g_q1cnt[qb], add);
        }
        __syncthreads();

        const int base = base_s;
        const int n = (cnt < LBUF1) ? cnt : LBUF1;
        for (int i = tid; i < n; i += 256) {
            const int o = base + i;
            if (o < QCAP1) g_q1list[qb * QCAP1 + o] = buf[i];
        }
    }
}

// ---------------------------------------------------------------------------
// Launch 3: knn1 merge (blocks 0..255) + grid scatter (blocks 256..295).
// ---------------------------------------------------------------------------
__global__ __launch_bounds__(256) void merge_scatter_kernel(
    const float* __restrict__ noisy,
    const float* __restrict__ clean)
{
    __shared__ unsigned long long keys[2048];
    const int blk = blockIdx.x;
    const int tid = threadIdx.x;

    if (blk >= 256) {
        // ------- scatter via low-contention cursor atomics (verbatim) -------
        const int idx = blk - 256;
        const int bb  = idx / GB_BLK;
        const int sb  = idx % GB_BLK;
        const float* cb = clean + bb * (N_PTS * 3);

        const int j0 = sb * GB_PER;
        for (int j = j0 + tid; j < j0 + GB_PER; j += 256) {
            const float x = cb[j * 3 + 0], y = cb[j * 3 + 1], z = cb[j * 3 + 2];
            const int c = cell_of(x, y, z);
            const int pos = atomicAdd(&g_cursor[bb * NCELL + c], 1);
            const float pp = fmaf(z, z, fmaf(y, y, x * x));
            g_cpts[bb * N_PTS + pos]  = make_float4(x, y, z, pp);
            g_cpidx[bb * N_PTS + pos] = j;
        }
        return;
    }

    // ------- knn1 merge: 512-key bitonic; inline exact fallback (verbatim) -------
    const int qb  = blk;
    const int cnt = g_q1cnt[qb];

    if (cnt >= 32 && cnt <= QCAP1) {
        for (int i = tid; i < QCAP1; i += 256)
            keys[i] = (i < cnt) ? g_q1list[qb * QCAP1 + i] : ~0ULL;
        __syncthreads();
        for (int k = 2; k <= QCAP1; k <<= 1) {
            for (int jj = k >> 1; jj > 0; jj >>= 1) {
                const int idx = tid;
                const int i = ((idx & ~(jj - 1)) << 1) | (idx & (jj - 1));
                const int partner = i | jj;
                const bool asc = ((i & k) == 0);
                const unsigned long long a = keys[i];
                const unsigned long long c = keys[partner];
                if ((a > c) == asc) { keys[i] = c; keys[partner] = a; }
                __syncthreads();
            }
        }
    } else {
        const int b = qb >> 7;
        const float* nb = noisy + b * (N_PTS * 3);
        const int si = g_sidx[qb & 127];
        const float qx = nb[si * 3 + 0];
        const float qy = nb[si * 3 + 1];
        const float qz = nb[si * 3 + 2];

        float bd[8]; int bi[8];
#pragma unroll
        for (int i = 0; i < 8; ++i) { bd[i] = BIGF; bi[i] = 0x7fffffff; }
        for (int j = tid; j < N_PTS; j += 256) {
            const float dx = qx - nb[j * 3 + 0];
            const float dy = qy - nb[j * 3 + 1];
            const float dz = qz - nb[j * 3 + 2];
            const float d2 = fmaf(dz, dz, fmaf(dy, dy, dx * dx));
            if (d2 < bd[7]) {
                bd[7] = d2; bi[7] = j;
#pragma unroll
                for (int t = 7; t > 0; --t) {
                    if (bd[t] < bd[t - 1]) {
                        float td = bd[t]; bd[t] = bd[t - 1]; bd[t - 1] = td;
                        int   ti = bi[t]; bi[t] = bi[t - 1]; bi[t - 1] = ti;
                    }
                }
            }
        }
#pragma unroll
        for (int t = 0; t < 8; ++t)
            keys[tid * 8 + t] = ((unsigned long long)__float_as_uint(bd[t]) << 32)
                              | (unsigned int)bi[t];
        __syncthreads();
        for (int k = 2; k <= 2048; k <<= 1) {
            for (int jj = k >> 1; jj > 0; jj >>= 1) {
#pragma unroll
                for (int base = 0; base < 2048; base += 256) {
                    const int i = base + tid;
                    const int partner = i ^ jj;
                    if (partner > i) {
                        const bool asc = ((i & k) == 0);
                        const unsigned long long a = keys[i];
                        const unsigned long long c = keys[partner];
                        if ((a > c) == asc) { keys[i] = c; keys[partner] = a; }
                    }
                }
                __syncthreads();
            }
        }
    }

    if (tid < 32) {
        const int idx = (int)(keys[tid] & 0xFFFFFFFFull);
        g_fidx[qb * 32 + tid] = clampi(idx, 0, N_PTS - 1);
    }
    if (tid == 0) g_q1cnt[qb] = 0;
}

// ---------------------------------------------------------------------------
// Launch 4: fused knn2 + loss (flattened 9-row all-lane walk; verbatim from
// the 107.8us champion).
// ---------------------------------------------------------------------------
__global__ __launch_bounds__(256) void knn2_loss_kernel(
    const float* __restrict__ noisy,
    const float* __restrict__ clean)
{
    __shared__ float2 buf[4][QCAP];    // 3 KB
    __shared__ int    bcnt[4];
    __shared__ float  red[4];
    const int tid  = threadIdx.x;
    const int wv   = tid >> 6;
    const int lane = tid & 63;
    const int g    = blockIdx.x * 4 + wv;
    const int b    = g >> 12;
    const int p    = (g >> 5) & 127;
    const float* nb = noisy + b * (N_PTS * 3);
    const float* cb = clean + b * (N_PTS * 3);

    if (lane == 0) bcnt[wv] = 0;

    const int fid = clampi(g_fidx[g], 0, N_PTS - 1);
    const float fx = nb[fid * 3 + 0];
    const float fy = nb[fid * 3 + 1];
    const float fz = nb[fid * 3 + 2];
    const float fm2x = -2.0f * fx, fm2y = -2.0f * fy, fm2z = -2.0f * fz;
    const float ff = fmaf(fz, fz, fmaf(fy, fy, fx * fx));
    const float taup = TAU2 - ff;

    const int cfx = clampi((int)(fx * NG), 0, NG - 1);
    const int cfy = clampi((int)(fy * NG), 0, NG - 1);
    const int cfz = clampi((int)(fz * NG), 0, NG - 1);
    const int bso = b * (NCELL + 1);
    const int bpo = b * N_PTS;

    // 9 rows (cy,cz); cells cxlo..cxhi are contiguous in the bin-sorted array.
    int s = 0, e = 0;
    if (lane < 9) {
        const int cy = cfy + (lane % 3) - 1;
        const int cz = cfz + (lane / 3) - 1;
        if (cy >= 0 && cy < NG && cz >= 0 && cz < NG) {
            const int cxlo = (cfx > 0) ? cfx - 1 : 0;
            const int cxhi = (cfx < NG - 1) ? cfx + 1 : NG - 1;
            const int rowb = NG * (cy + NG * cz);
            s = g_binstart[bso + cxlo + rowb];
            e = g_binstart[bso + cxhi + rowb + 1];
        }
    }
    const int len = e - s;
    int incl = len;
#pragma unroll
    for (int off = 1; off < 16; off <<= 1) {
        const int nsh = __shfl_up(incl, off);
        if (lane >= off) incl += nsh;
    }
    const int T = __shfl(incl, 8);
    const int pfx = incl - len;          // exclusive prefix for this lane's row

    int rp[9], rs[9];
#pragma unroll
    for (int i = 0; i < 9; ++i) {
        rp[i] = __shfl(pfx, i);
        rs[i] = __shfl(s, i);
    }

    for (int t = lane; t < T; t += 64) {
        int base = rs[0], pref = rp[0];
#pragma unroll
        for (int i = 1; i < 9; ++i) {    // last row with rp[i] <= t (skips len-0 rows)
            const bool gsel = (t >= rp[i]);
            base = gsel ? rs[i] : base;
            pref = gsel ? rp[i] : pref;
        }
        const int k = base + (t - pref);
        const float4 pt = g_cpts[bpo + k];
        const float d2 = fmaf(fm2x, pt.x, fmaf(fm2y, pt.y, fmaf(fm2z, pt.z, pt.w)));
        if (d2 < taup) {
            const int slot = atomicAdd(&bcnt[wv], 1);
            if (slot < QCAP)
                buf[wv][slot] = make_float2(d2, __int_as_float(g_cpidx[bpo + k]));
        }
    }
    __syncthreads();

    // ------- loss: wave butterfly top-4 from the LDS list; exact fallback -------
    const int cnt = bcnt[wv];
    int nn[4];

    if (cnt >= 4 && cnt <= QCAP) {
        unsigned long long e0 = ~0ULL, e1 = ~0ULL;
        if (lane < cnt) {
            const float2 a = buf[wv][lane];
            e0 = packkey(a.x, __float_as_int(a.y));
        }
        if (lane + 64 < cnt) {
            const float2 a = buf[wv][lane + 64];
            e1 = packkey(a.x, __float_as_int(a.y));
        }
        if (e1 < e0) { unsigned long long t = e0; e0 = e1; e1 = t; }

        int c = 0;
#pragma unroll
        for (int r = 0; r < 4; ++r) {
            const unsigned long long h = (c == 0) ? e0 : ((c == 1) ? e1 : ~0ULL);
            unsigned long long m = h;
#pragma unroll
            for (int off = 32; off; off >>= 1) {
                const unsigned long long o = __shfl_xor(m, off);
                if (o < m) m = o;
            }
            if (h == m) c++;
            nn[r] = (int)(m & 0xFFFFFFFFull);
        }
    } else {
        float bd[4]; int bi[4];
#pragma unroll
        for (int t = 0; t < 4; ++t) { bd[t] = BIGF; bi[t] = 0x7fffffff; }
        for (int j = lane; j < N_PTS; j += 64) {
            const float dx = fx - cb[j * 3 + 0];
            const float dy = fy - cb[j * 3 + 1];
            const float dz = fz - cb[j * 3 + 2];
            const float d2 = fmaf(dz, dz, fmaf(dy, dy, dx * dx));
            if (d2 < bd[3]) {
                bd[3] = d2; bi[3] = j;
#pragma unroll
                for (int t = 3; t > 0; --t) {
                    if (bd[t] < bd[t - 1]) {
                        float td = bd[t]; bd[t] = bd[t - 1]; bd[t - 1] = td;
                        int   ti = bi[t]; bi[t] = bi[t - 1]; bi[t - 1] = ti;
                    }
                }
            }
        }
        int cur = 0;
        for (int r = 0; r < 4; ++r) {
            float v  = (cur < 4) ? bd[cur] : BIGF;
            int   vi = (cur < 4) ? bi[cur] : 0x7fffffff;
            int   who = lane;
#pragma unroll
            for (int off = 32; off; off >>= 1) {
                const float v2  = __shfl_down(v, off);
                const int   vi2 = __shfl_down(vi, off);
                const int   w2  = __shfl_down(who, off);
                if (v2 < v || (v2 == v && vi2 < vi)) { v = v2; vi = vi2; who = w2; }
            }
            const int bvi = __shfl(vi, 0);
            const int bwh = __shfl(who, 0);
            nn[r] = bvi;
            if (lane == bwh) cur++;
        }
    }

    float t2 = 0.0f;
    if (lane == 0) {
        const int si = g_sidx[p];
        const float qx = nb[si * 3 + 0], qy = nb[si * 3 + 1], qz = nb[si * 3 + 2];
        const int n0 = clampi(nn[0], 0, N_PTS - 1), n1 = clampi(nn[1], 0, N_PTS - 1);
        const int n2 = clampi(nn[2], 0, N_PTS - 1), n3 = clampi(nn[3], 0, N_PTS - 1);
        const float mx = 0.25f * (cb[n0*3+0] + cb[n1*3+0] + cb[n2*3+0] + cb[n3*3+0]);
        const float my = 0.25f * (cb[n0*3+1] + cb[n1*3+1] + cb[n2*3+1] + cb[n3*3+1]);
        const float mz = 0.25f * (cb[n0*3+2] + cb[n1*3+2] + cb[n2*3+2] + cb[n3*3+2]);

        const float gx = mx - fx, gy = my - fy, gz = mz - fz;
        const float rx = fx - qx, ry = fy - qy, rz = fz - qz;
        const float ex = rx * g_WxS[0] + ry * g_WxS[3] + rz * g_WxS[6] + qx * g_M3[0] + qy * g_M3[3] + qz * g_M3[6];
        const float ey = rx * g_WxS[1] + ry * g_WxS[4] + rz * g_WxS[7] + qx * g_M3[1] + qy * g_M3[4] + qz * g_M3[7];
        const float ez = rx * g_WxS[2] + ry * g_WxS[5] + rz * g_WxS[8] + qx * g_M3[2] + qy * g_M3[5] + qz * g_M3[8];
        const float dx = ex - gx, dy = ey - gy, dz = ez - gz;
        t2 = dx * dx + dy * dy + dz * dz;
    }

    if (lane == 0) red[wv] = t2;
    __syncthreads();
    if (tid == 0) g_lploss[blockIdx.x] = (red[0] + red[1]) + (red[2] + red[3]);
}

// ---------------------------------------------------------------------------
// Launch 5: sum 2048 per-block partials (1 block, 256 thr). Proven cheaper
// than every in-kernel finisher variant (R1/R5/R6).
// ---------------------------------------------------------------------------
__global__ __launch_bounds__(256) void final_kernel(float* __restrict__ out)
{
    __shared__ float red[4];
    const int tid = threadIdx.x;
    float v = 0.0f;
    for (int i = tid; i < NLOSSB; i += 256) v += g_lploss[i];
#pragma unroll
    for (int off = 32; off; off >>= 1) v += __shfl_down(v, off);
    if ((tid & 63) == 0) red[tid >> 6] = v;
    __syncthreads();
    if (tid == 0) out[0] = ((red[0] + red[1]) + (red[2] + red[3])) * (50.0f / 8192.0f);
}

extern "C" void kernel_launch(void* const* d_in, const int* in_sizes, int n_in,
                              void* d_out, int out_size, void* d_ws, size_t ws_size,
                              hipStream_t stream)
{
    (void)d_ws; (void)ws_size; (void)in_sizes; (void)n_in; (void)out_size;

    const float* noisy = (const float*)d_in[0];
    const float* clean = (const float*)d_in[1];
    const float* Wf    = (const float*)d_in[3];
    const float* Wx    = (const float*)d_in[4];
    const float* Wc    = (const float*)d_in[5];

    // 1: hist (40 blocks) + sidx/M3 decode (1 block)
    setup_kernel<<<N_B * GB_BLK + 1, 256, 0, stream>>>(clean, d_in[2], Wf, Wx, Wc);
    // 2: prefix scan (2 blocks) + knn1 tau-scan, quad-vectorized (2048 blocks)
    scan_knn1_kernel<<<N_B + 256 * K1SUB, 256, 0, stream>>>(noisy);
    // 3: knn1 merge (256 blocks) + scatter (40 blocks)
    merge_scatter_kernel<<<256 + N_B * GB_BLK, 256, 0, stream>>>(noisy, clean);
    // 4: fused knn2 + loss (2048 blocks, flattened 9-row walk)
    knn2_loss_kernel<<<NLOSSB, 256, 0, stream>>>(noisy, clean);
    // 5: final reduction (1 block)
    final_kernel<<<1, 256, 0, stream>>>((float*)d_out);
}